// Round 10
// baseline (1623.460 us; speedup 1.0000x reference)
//
#include <hip/hip_runtime.h>
#include <math.h>

// ---------------------------------------------------------------------------
// 3-layer GCN on MI355X, fused aggregate-then-GEMM form.
//   out = relu( (A_hat @ in) @ W + b ),  A_hat = D^-1/2 (A+I) D^-1/2
// bf16 prescaled gather rows (s = bf16(dinv*h), 256B/row), gathered 8B/lane,
// two 32-lane halves fetch TWO edges per VMEM instruction (128B quarter-wave
// requests -> no fetch amplification).
// Round-10: batch-issue 12 independent pair-gathers into registers BEFORE
// consuming (fixes round-8's exposed latency, VALUBusy 16%) WITHOUT round-9's
// cross-node pipeline rotation (which diverged on replay). No carried state,
// no speculative prefetch, nothing uninitialized on any path.
// CSR over dst rebuilt on-device every call.
// ---------------------------------------------------------------------------

__device__ __forceinline__ unsigned short f2bf(float f) {
  unsigned u = __float_as_uint(f);
  return (unsigned short)((u + 0x7FFFu + ((u >> 16) & 1u)) >> 16);
}
__device__ __forceinline__ float bfLo(unsigned v) { return __uint_as_float(v << 16); }
__device__ __forceinline__ float bfHi(unsigned v) { return __uint_as_float(v & 0xFFFF0000u); }

// ------------------------------- CSR build ---------------------------------

__global__ __launch_bounds__(256) void k_zero(int* __restrict__ cnt,
                                              int* __restrict__ fillPos, int n) {
  int i = blockIdx.x * blockDim.x + threadIdx.x;
  if (i < n) { cnt[i] = 0; fillPos[i] = 0; }
}

__global__ __launch_bounds__(256) void k_deg(const int* __restrict__ dst,
                                             int* __restrict__ cnt, int E) {
  int i = blockIdx.x * blockDim.x + threadIdx.x;
  int stride = gridDim.x * blockDim.x;
  for (; i < E; i += stride) atomicAdd(&cnt[dst[i]], 1);
}

__global__ __launch_bounds__(256) void k_dinv(const int* __restrict__ cnt,
                                              float* __restrict__ dinv, int n) {
  int i = blockIdx.x * blockDim.x + threadIdx.x;
  if (i < n) dinv[i] = rsqrtf(1.0f + (float)cnt[i]);
}

__global__ __launch_bounds__(256) void k_scan1(const int* __restrict__ cnt,
                                               int* __restrict__ exc,
                                               int* __restrict__ bsum, int n) {
  __shared__ int lds[256];
  int t = threadIdx.x;
  int base = blockIdx.x * 1024 + t * 4;
  int v0 = (base + 0 < n) ? cnt[base + 0] : 0;
  int v1 = (base + 1 < n) ? cnt[base + 1] : 0;
  int v2 = (base + 2 < n) ? cnt[base + 2] : 0;
  int v3 = (base + 3 < n) ? cnt[base + 3] : 0;
  int sum = v0 + v1 + v2 + v3;
  lds[t] = sum;
  __syncthreads();
  for (int off = 1; off < 256; off <<= 1) {
    int val = lds[t];
    if (t >= off) val += lds[t - off];
    __syncthreads();
    lds[t] = val;
    __syncthreads();
  }
  int ex = lds[t] - sum;
  if (base + 0 < n) exc[base + 0] = ex;
  ex += v0;
  if (base + 1 < n) exc[base + 1] = ex;
  ex += v1;
  if (base + 2 < n) exc[base + 2] = ex;
  ex += v2;
  if (base + 3 < n) exc[base + 3] = ex;
  if (t == 255) bsum[blockIdx.x] = lds[255];
}

__global__ __launch_bounds__(128) void k_scan2(int* __restrict__ bsum, int nb) {
  __shared__ int lds[128];
  int t = threadIdx.x;
  int v = (t < nb) ? bsum[t] : 0;
  lds[t] = v;
  __syncthreads();
  for (int off = 1; off < 128; off <<= 1) {
    int val = lds[t];
    if (t >= off) val += lds[t - off];
    __syncthreads();
    lds[t] = val;
    __syncthreads();
  }
  if (t < nb) bsum[t] = lds[t] - v;
}

__global__ __launch_bounds__(256) void k_scan3(int* __restrict__ exc,
                                               const int* __restrict__ bsum, int n) {
  int i = blockIdx.x * blockDim.x + threadIdx.x;
  if (i < n) exc[i] += bsum[i >> 10];
}

__global__ __launch_bounds__(256) void k_fill(const int* __restrict__ src,
                                              const int* __restrict__ dst,
                                              const int* __restrict__ rowStart,
                                              int* __restrict__ fillPos,
                                              int* __restrict__ eSrc, int E) {
  int i = blockIdx.x * blockDim.x + threadIdx.x;
  int stride = gridDim.x * blockDim.x;
  for (; i < E; i += stride) {
    int d = dst[i];
    int p = rowStart[d] + atomicAdd(&fillPos[d], 1);
    eSrc[p] = src[i];
  }
}

// ---------------- bf16 prescale: s = bf16(dinv * h), 256B rows -------------

__global__ __launch_bounds__(256) void k_scale(const float* __restrict__ h,
                                               const float* __restrict__ dinv,
                                               uint4* __restrict__ s4, int nQuads) {
  int i = blockIdx.x * blockDim.x + threadIdx.x;
  int stride = gridDim.x * blockDim.x;
  for (; i < nQuads; i += stride) {
    int row = i >> 4;
    int q = i & 15;
    float dv = dinv[row];
    const float4* hp = (const float4*)&h[(size_t)row * 128 + 8 * q];
    float4 a = hp[0], b = hp[1];
    uint4 o;
    o.x = (unsigned)f2bf(dv * a.x) | ((unsigned)f2bf(dv * a.y) << 16);
    o.y = (unsigned)f2bf(dv * a.z) | ((unsigned)f2bf(dv * a.w) << 16);
    o.z = (unsigned)f2bf(dv * b.x) | ((unsigned)f2bf(dv * b.y) << 16);
    o.w = (unsigned)f2bf(dv * b.z) | ((unsigned)f2bf(dv * b.w) << 16);
    s4[i] = o;
  }
}

// ------- fused layer: batched gather issue, 2 edges per VMEM, no pipeline --
// Lane l: half = l>>5, sl = l&31; lane owns bf16 cols 4*sl..4*sl+3.
// Per node: idx vector -> 12 clamped pair-gathers g[0..11] (24 edges, all
// independent loads) -> mask-zero invalid on consume -> round-8 pair tail
// for c>24 -> shfl GEMM vs LDS W -> store.
static constexpr int NP = 12;

template <int NFO, bool RELU>
__global__ __launch_bounds__(512) void k_layer_bf3(const unsigned* __restrict__ sU,
                                                   const float* __restrict__ W,
                                                   const float* __restrict__ bias,
                                                   const float* __restrict__ dinv,
                                                   const int* __restrict__ eSrc,
                                                   const int* __restrict__ rowStart,
                                                   const int* __restrict__ cnt,
                                                   float* __restrict__ out, int n) {
  __shared__ float Wl[128 * NFO];
  for (int t = threadIdx.x; t < 128 * NFO; t += 512) Wl[t] = W[t];
  __syncthreads();
  const int wid = threadIdx.x >> 6, lane = threadIdx.x & 63;
  const int half = lane >> 5, sl = lane & 31;
  for (int node = blockIdx.x * 8 + wid; node < n; node += gridDim.x * 8) {
    const int st = rowStart[node], c = cnt[node];
    const float dv = dinv[node];
    const int cl = c < 64 ? c : 64;
    int myIdx = (lane < cl) ? eSrc[st + lane] : 0;

    // ---- issue: self + 12 pair-gathers, all independent ----
    uint2 self = *(const uint2*)&sU[(size_t)node * 64 + 2 * sl];
    uint2 g[NP];
    #pragma unroll
    for (int p = 0; p < NP; p++) {
      int iA = __shfl(myIdx, 2 * p);
      int iB = __shfl(myIdx, 2 * p + 1);
      int x = half ? iB : iA;  // lanes >= cl carry idx 0 -> row 0, zeroed below
      g[p] = *(const uint2*)&sU[(size_t)x * 64 + 2 * sl];
    }

    // ---- consume ----
    float a0, a1, a2, a3;
    if (half == 0) {
      a0 = bfLo(self.x); a1 = bfHi(self.x); a2 = bfLo(self.y); a3 = bfHi(self.y);
    } else {
      a0 = a1 = a2 = a3 = 0.f;
    }
    #pragma unroll
    for (int p = 0; p < NP; p++) {
      uint2 gv = g[p];
      bool ok = (2 * p + half) < c;
      gv.x = ok ? gv.x : 0u;
      gv.y = ok ? gv.y : 0u;
      a0 += bfLo(gv.x); a1 += bfHi(gv.x); a2 += bfLo(gv.y); a3 += bfHi(gv.y);
    }
    // tail (c > 24): verbatim round-8 pair loop starting at j = 24
    const int* es = eSrc + st;
    for (int j = 2 * NP; j < c; j += 2) {
      int iA = (j < cl) ? __shfl(myIdx, j) : es[j];
      int hasB = (j + 1 < c);
      int iB = hasB ? ((j + 1 < cl) ? __shfl(myIdx, j + 1) : es[j + 1]) : iA;
      int x = half ? iB : iA;
      uint2 v = *(const uint2*)&sU[(size_t)x * 64 + 2 * sl];
      if (half && !hasB) { v.x = 0u; v.y = 0u; }
      a0 += bfLo(v.x); a1 += bfHi(v.x); a2 += bfLo(v.y); a3 += bfHi(v.y);
    }
    a0 += __shfl_xor(a0, 32);
    a1 += __shfl_xor(a1, 32);
    a2 += __shfl_xor(a2, 32);
    a3 += __shfl_xor(a3, 32);
    a0 *= dv; a1 *= dv; a2 *= dv; a3 *= dv;  // t[4*sl + r]

    // ---- row-GEMM vs LDS W; t[4q+r] read from lane q ----
    if constexpr (NFO == 128) {
      float o0 = 0.f, o1 = 0.f;
      #pragma unroll
      for (int q = 0; q < 32; q++) {
        float t0 = __shfl(a0, q);
        float t1 = __shfl(a1, q);
        float t2 = __shfl(a2, q);
        float t3 = __shfl(a3, q);
        float2 w0 = *(const float2*)&Wl[(4 * q + 0) * 128 + 2 * lane];
        float2 w1 = *(const float2*)&Wl[(4 * q + 1) * 128 + 2 * lane];
        float2 w2 = *(const float2*)&Wl[(4 * q + 2) * 128 + 2 * lane];
        float2 w3 = *(const float2*)&Wl[(4 * q + 3) * 128 + 2 * lane];
        o0 = fmaf(t0, w0.x, o0); o1 = fmaf(t0, w0.y, o1);
        o0 = fmaf(t1, w1.x, o0); o1 = fmaf(t1, w1.y, o1);
        o0 = fmaf(t2, w2.x, o0); o1 = fmaf(t2, w2.y, o1);
        o0 = fmaf(t3, w3.x, o0); o1 = fmaf(t3, w3.y, o1);
      }
      float2 bb = *(const float2*)&bias[2 * lane];
      float r0 = o0 + bb.x, r1 = o1 + bb.y;
      if (RELU) { r0 = fmaxf(r0, 0.f); r1 = fmaxf(r1, 0.f); }
      *(float2*)&out[(size_t)node * 128 + 2 * lane] = make_float2(r0, r1);
    } else {
      float o0 = 0.f;
      #pragma unroll
      for (int q = 0; q < 32; q++) {
        float t0 = __shfl(a0, q);
        float t1 = __shfl(a1, q);
        float t2 = __shfl(a2, q);
        float t3 = __shfl(a3, q);
        o0 = fmaf(t0, Wl[(4 * q + 0) * NFO + lane], o0);
        o0 = fmaf(t1, Wl[(4 * q + 1) * NFO + lane], o0);
        o0 = fmaf(t2, Wl[(4 * q + 2) * NFO + lane], o0);
        o0 = fmaf(t3, Wl[(4 * q + 3) * NFO + lane], o0);
      }
      float r0 = o0 + bias[lane];
      if (RELU) r0 = fmaxf(r0, 0.f);
      out[(size_t)node * NFO + lane] = r0;
    }
  }
}

// --------------------- fp32 fused kernel (ws-fallback) ---------------------

template <int NFO, bool RELU>
__global__ __launch_bounds__(512) void k_layer_f32(const float* __restrict__ in,
                                                   const float* __restrict__ W,
                                                   const float* __restrict__ bias,
                                                   const float* __restrict__ dinv,
                                                   const int* __restrict__ eSrc,
                                                   const int* __restrict__ rowStart,
                                                   const int* __restrict__ cnt,
                                                   float* __restrict__ out, int n) {
  __shared__ float Wl[128 * NFO];
  for (int t = threadIdx.x; t < 128 * NFO; t += 512) Wl[t] = W[t];
  __syncthreads();
  const int wid = threadIdx.x >> 6, lane = threadIdx.x & 63;
  for (int node = blockIdx.x * 8 + wid; node < n; node += gridDim.x * 8) {
    const int s = rowStart[node], c = cnt[node];
    const int* es = eSrc + s;
    const float dv = dinv[node];
    float2 x2 = *(const float2*)&in[(size_t)node * 128 + 2 * lane];
    float ax = dv * x2.x, ay = dv * x2.y;
    int j = 0;
    for (; j + 4 <= c; j += 4) {
      int s0 = es[j], s1 = es[j + 1], s2 = es[j + 2], s3 = es[j + 3];
      float d0 = dinv[s0], d1 = dinv[s1], d2 = dinv[s2], d3 = dinv[s3];
      float2 v0 = *(const float2*)&in[(size_t)s0 * 128 + 2 * lane];
      float2 v1 = *(const float2*)&in[(size_t)s1 * 128 + 2 * lane];
      float2 v2 = *(const float2*)&in[(size_t)s2 * 128 + 2 * lane];
      float2 v3 = *(const float2*)&in[(size_t)s3 * 128 + 2 * lane];
      ax = fmaf(d0, v0.x, ax); ay = fmaf(d0, v0.y, ay);
      ax = fmaf(d1, v1.x, ax); ay = fmaf(d1, v1.y, ay);
      ax = fmaf(d2, v2.x, ax); ay = fmaf(d2, v2.y, ay);
      ax = fmaf(d3, v3.x, ax); ay = fmaf(d3, v3.y, ay);
    }
    for (; j < c; j++) {
      int sj = es[j];
      float dj = dinv[sj];
      float2 v = *(const float2*)&in[(size_t)sj * 128 + 2 * lane];
      ax = fmaf(dj, v.x, ax); ay = fmaf(dj, v.y, ay);
    }
    ax *= dv; ay *= dv;
    if constexpr (NFO == 128) {
      float o0 = 0.f, o1 = 0.f;
      #pragma unroll
      for (int kk = 0; kk < 64; kk++) {
        float xa = __shfl(ax, kk);
        float xb = __shfl(ay, kk);
        float2 wA = *(const float2*)&Wl[(2 * kk) * 128 + 2 * lane];
        float2 wB = *(const float2*)&Wl[(2 * kk + 1) * 128 + 2 * lane];
        o0 = fmaf(xa, wA.x, o0); o1 = fmaf(xa, wA.y, o1);
        o0 = fmaf(xb, wB.x, o0); o1 = fmaf(xb, wB.y, o1);
      }
      float2 bb = *(const float2*)&bias[2 * lane];
      float r0 = o0 + bb.x, r1 = o1 + bb.y;
      if (RELU) { r0 = fmaxf(r0, 0.f); r1 = fmaxf(r1, 0.f); }
      *(float2*)&out[(size_t)node * 128 + 2 * lane] = make_float2(r0, r1);
    } else {
      float o0 = 0.f;
      #pragma unroll
      for (int kk = 0; kk < 64; kk++) {
        float xa = __shfl(ax, kk);
        float xb = __shfl(ay, kk);
        o0 = fmaf(xa, Wl[(2 * kk) * NFO + lane], o0);
        o0 = fmaf(xb, Wl[(2 * kk + 1) * NFO + lane], o0);
      }
      float r0 = o0 + bias[lane];
      if (RELU) r0 = fmaxf(r0, 0.f);
      out[(size_t)node * NFO + lane] = r0;
    }
  }
}

// ---------------------------------------------------------------------------

extern "C" void kernel_launch(void* const* d_in, const int* in_sizes, int n_in,
                              void* d_out, int out_size, void* d_ws, size_t ws_size,
                              hipStream_t stream) {
  const float* x  = (const float*)d_in[0];
  const int*   ei = (const int*)d_in[1];
  const float* W1 = (const float*)d_in[2];
  const float* b1 = (const float*)d_in[3];
  const float* W2 = (const float*)d_in[4];
  const float* b2 = (const float*)d_in[5];
  const float* W3 = (const float*)d_in[6];
  const float* b3 = (const float*)d_in[7];

  const int N = in_sizes[0] / 128;
  const int E = in_sizes[1] / 2;
  const int* src = ei;
  const int* dst = ei + E;

  char* ws = (char*)d_ws;
  size_t off = 0;
  auto alloc = [&](size_t bytes) -> void* {
    void* p = ws + off;
    off = (off + bytes + 255) & ~(size_t)255;
    return p;
  };
  int*   cnt      = (int*)alloc((size_t)N * 4);
  int*   fillPos  = (int*)alloc((size_t)N * 4);
  int*   rowStart = (int*)alloc((size_t)N * 4);
  float* dinv     = (float*)alloc((size_t)N * 4);
  int*   bsum     = (int*)alloc(512);
  int*   eSrc     = (int*)alloc((size_t)E * 4);
  unsigned* sU    = (unsigned*)alloc((size_t)N * 64 * 4);  // bf16 rows, 256B
  const bool fast = (ws_size >= off);                       // ~33.7 MB

  float* y    = (float*)d_out;          // [N,64]
  float* out1 = y + (size_t)N * 64;     // [N,128]
  float* out2 = out1 + (size_t)N * 128; // [N,128]

  // ---- CSR build ----
  k_zero<<<(N + 255) / 256, 256, 0, stream>>>(cnt, fillPos, N);
  k_deg<<<2048, 256, 0, stream>>>(dst, cnt, E);
  k_dinv<<<(N + 255) / 256, 256, 0, stream>>>(cnt, dinv, N);
  int nChunks = (N + 1023) / 1024;
  k_scan1<<<nChunks, 256, 0, stream>>>(cnt, rowStart, bsum, N);
  k_scan2<<<1, 128, 0, stream>>>(bsum, nChunks);
  k_scan3<<<(N + 255) / 256, 256, 0, stream>>>(rowStart, bsum, N);
  k_fill<<<2048, 256, 0, stream>>>(src, dst, rowStart, fillPos, eSrc, E);

  // ---- layers ----
  if (fast) {
    const int nQuads = N * 16;
    const int sBlocks = (nQuads + 255) / 256;
    k_scale<<<sBlocks, 256, 0, stream>>>(x, dinv, (uint4*)sU, nQuads);
    k_layer_bf3<128, true ><<<1024, 512, 0, stream>>>(sU, W1, b1, dinv, eSrc, rowStart, cnt, out1, N);
    k_scale<<<sBlocks, 256, 0, stream>>>(out1, dinv, (uint4*)sU, nQuads);
    k_layer_bf3<128, true ><<<1024, 512, 0, stream>>>(sU, W2, b2, dinv, eSrc, rowStart, cnt, out2, N);
    k_scale<<<sBlocks, 256, 0, stream>>>(out2, dinv, (uint4*)sU, nQuads);
    k_layer_bf3<64,  false><<<1024, 512, 0, stream>>>(sU, W3, b3, dinv, eSrc, rowStart, cnt, y,    N);
  } else {
    k_layer_f32<128, true ><<<1024, 512, 0, stream>>>(x,    W1, b1, dinv, eSrc, rowStart, cnt, out1, N);
    k_layer_f32<128, true ><<<1024, 512, 0, stream>>>(out1, W2, b2, dinv, eSrc, rowStart, cnt, out2, N);
    k_layer_f32<64,  false><<<1024, 512, 0, stream>>>(out2, W3, b3, dinv, eSrc, rowStart, cnt, y,    N);
  }
}

// Round 11
// 1615.720 us; speedup vs baseline: 1.0048x; 1.0048x over previous
//
#include <hip/hip_runtime.h>
#include <math.h>

// ---------------------------------------------------------------------------
// 3-layer GCN on MI355X, fused aggregate-then-GEMM form.
//   out = relu( (A_hat @ in) @ W + b ),  A_hat = D^-1/2 (A+I) D^-1/2
// bf16 prescaled gather rows (s = bf16(dinv*h), 256B/row), 8B/lane, two
// 32-lane halves fetch TWO edges per VMEM instruction (128B quarter-wave
// requests). Round-11: batch-issue up to 12 pair-gathers with EXACT
// addresses -- pair p is issued only if 2p < cl (wave-uniform branch, no
// divergence), odd-c B-slots reuse edge A instead of clamping to row 0.
// Round-10 showed batching lifts delivered rate 1.15->2.1 TB/s but slop
// loads tripled FETCH; this keeps the rate and restores bf2's exact bytes.
// CSR over dst rebuilt on-device every call.
// ---------------------------------------------------------------------------

__device__ __forceinline__ unsigned short f2bf(float f) {
  unsigned u = __float_as_uint(f);
  return (unsigned short)((u + 0x7FFFu + ((u >> 16) & 1u)) >> 16);
}
__device__ __forceinline__ float bfLo(unsigned v) { return __uint_as_float(v << 16); }
__device__ __forceinline__ float bfHi(unsigned v) { return __uint_as_float(v & 0xFFFF0000u); }

// ------------------------------- CSR build ---------------------------------

__global__ __launch_bounds__(256) void k_zero(int* __restrict__ cnt,
                                              int* __restrict__ fillPos, int n) {
  int i = blockIdx.x * blockDim.x + threadIdx.x;
  if (i < n) { cnt[i] = 0; fillPos[i] = 0; }
}

__global__ __launch_bounds__(256) void k_deg(const int* __restrict__ dst,
                                             int* __restrict__ cnt, int E) {
  int i = blockIdx.x * blockDim.x + threadIdx.x;
  int stride = gridDim.x * blockDim.x;
  for (; i < E; i += stride) atomicAdd(&cnt[dst[i]], 1);
}

__global__ __launch_bounds__(256) void k_dinv(const int* __restrict__ cnt,
                                              float* __restrict__ dinv, int n) {
  int i = blockIdx.x * blockDim.x + threadIdx.x;
  if (i < n) dinv[i] = rsqrtf(1.0f + (float)cnt[i]);
}

__global__ __launch_bounds__(256) void k_scan1(const int* __restrict__ cnt,
                                               int* __restrict__ exc,
                                               int* __restrict__ bsum, int n) {
  __shared__ int lds[256];
  int t = threadIdx.x;
  int base = blockIdx.x * 1024 + t * 4;
  int v0 = (base + 0 < n) ? cnt[base + 0] : 0;
  int v1 = (base + 1 < n) ? cnt[base + 1] : 0;
  int v2 = (base + 2 < n) ? cnt[base + 2] : 0;
  int v3 = (base + 3 < n) ? cnt[base + 3] : 0;
  int sum = v0 + v1 + v2 + v3;
  lds[t] = sum;
  __syncthreads();
  for (int off = 1; off < 256; off <<= 1) {
    int val = lds[t];
    if (t >= off) val += lds[t - off];
    __syncthreads();
    lds[t] = val;
    __syncthreads();
  }
  int ex = lds[t] - sum;
  if (base + 0 < n) exc[base + 0] = ex;
  ex += v0;
  if (base + 1 < n) exc[base + 1] = ex;
  ex += v1;
  if (base + 2 < n) exc[base + 2] = ex;
  ex += v2;
  if (base + 3 < n) exc[base + 3] = ex;
  if (t == 255) bsum[blockIdx.x] = lds[255];
}

__global__ __launch_bounds__(128) void k_scan2(int* __restrict__ bsum, int nb) {
  __shared__ int lds[128];
  int t = threadIdx.x;
  int v = (t < nb) ? bsum[t] : 0;
  lds[t] = v;
  __syncthreads();
  for (int off = 1; off < 128; off <<= 1) {
    int val = lds[t];
    if (t >= off) val += lds[t - off];
    __syncthreads();
    lds[t] = val;
    __syncthreads();
  }
  if (t < nb) bsum[t] = lds[t] - v;
}

__global__ __launch_bounds__(256) void k_scan3(int* __restrict__ exc,
                                               const int* __restrict__ bsum, int n) {
  int i = blockIdx.x * blockDim.x + threadIdx.x;
  if (i < n) exc[i] += bsum[i >> 10];
}

__global__ __launch_bounds__(256) void k_fill(const int* __restrict__ src,
                                              const int* __restrict__ dst,
                                              const int* __restrict__ rowStart,
                                              int* __restrict__ fillPos,
                                              int* __restrict__ eSrc, int E) {
  int i = blockIdx.x * blockDim.x + threadIdx.x;
  int stride = gridDim.x * blockDim.x;
  for (; i < E; i += stride) {
    int d = dst[i];
    int p = rowStart[d] + atomicAdd(&fillPos[d], 1);
    eSrc[p] = src[i];
  }
}

// ---------------- bf16 prescale: s = bf16(dinv * h), 256B rows -------------

__global__ __launch_bounds__(256) void k_scale(const float* __restrict__ h,
                                               const float* __restrict__ dinv,
                                               uint4* __restrict__ s4, int nQuads) {
  int i = blockIdx.x * blockDim.x + threadIdx.x;
  int stride = gridDim.x * blockDim.x;
  for (; i < nQuads; i += stride) {
    int row = i >> 4;
    int q = i & 15;
    float dv = dinv[row];
    const float4* hp = (const float4*)&h[(size_t)row * 128 + 8 * q];
    float4 a = hp[0], b = hp[1];
    uint4 o;
    o.x = (unsigned)f2bf(dv * a.x) | ((unsigned)f2bf(dv * a.y) << 16);
    o.y = (unsigned)f2bf(dv * a.z) | ((unsigned)f2bf(dv * a.w) << 16);
    o.z = (unsigned)f2bf(dv * b.x) | ((unsigned)f2bf(dv * b.y) << 16);
    o.w = (unsigned)f2bf(dv * b.z) | ((unsigned)f2bf(dv * b.w) << 16);
    s4[i] = o;
  }
}

// -------- fused layer: exact batched gather, 2 edges per VMEM --------------
// Lane l: half = l>>5, sl = l&31; lane owns bf16 cols 4*sl..4*sl+3.
// Pair p issued iff 2p < cl (wave-uniform). Odd-c B-slot loads edge A's row
// (masked to zero on consume) instead of clamping to row 0.
static constexpr int NP = 12;

template <int NFO, bool RELU>
__global__ __launch_bounds__(512) void k_layer_bf4(const unsigned* __restrict__ sU,
                                                   const float* __restrict__ W,
                                                   const float* __restrict__ bias,
                                                   const float* __restrict__ dinv,
                                                   const int* __restrict__ eSrc,
                                                   const int* __restrict__ rowStart,
                                                   const int* __restrict__ cnt,
                                                   float* __restrict__ out, int n) {
  __shared__ float Wl[128 * NFO];
  for (int t = threadIdx.x; t < 128 * NFO; t += 512) Wl[t] = W[t];
  __syncthreads();
  const int wid = threadIdx.x >> 6, lane = threadIdx.x & 63;
  const int half = lane >> 5, sl = lane & 31;
  for (int node = blockIdx.x * 8 + wid; node < n; node += gridDim.x * 8) {
    const int st = rowStart[node], c = cnt[node];
    const float dv = dinv[node];
    const int cl = c < 64 ? c : 64;
    int myIdx = (lane < cl) ? eSrc[st + lane] : 0;

    // ---- issue: self + up to 12 pair-gathers, exact addresses only ----
    uint2 self = *(const uint2*)&sU[(size_t)node * 64 + 2 * sl];
    uint2 g[NP];
    #pragma unroll
    for (int p = 0; p < NP; p++) {
      if (2 * p < cl) {  // wave-uniform: no divergence, no request if false
        int iA = __shfl(myIdx, 2 * p);
        int iB = (2 * p + 1 < cl) ? __shfl(myIdx, 2 * p + 1) : iA;
        int x = half ? iB : iA;
        g[p] = *(const uint2*)&sU[(size_t)x * 64 + 2 * sl];
      } else {
        g[p].x = 0u; g[p].y = 0u;
      }
    }

    // ---- consume ----
    float a0, a1, a2, a3;
    if (half == 0) {
      a0 = bfLo(self.x); a1 = bfHi(self.x); a2 = bfLo(self.y); a3 = bfHi(self.y);
    } else {
      a0 = a1 = a2 = a3 = 0.f;
    }
    #pragma unroll
    for (int p = 0; p < NP; p++) {
      uint2 gv = g[p];
      bool ok = (2 * p + half) < c;
      gv.x = ok ? gv.x : 0u;
      gv.y = ok ? gv.y : 0u;
      a0 += bfLo(gv.x); a1 += bfHi(gv.x); a2 += bfLo(gv.y); a3 += bfHi(gv.y);
    }
    // tail (c > 24): pair loop from j = 24 (verbatim round-8 structure)
    const int* es = eSrc + st;
    for (int j = 2 * NP; j < c; j += 2) {
      int iA = (j < cl) ? __shfl(myIdx, j) : es[j];
      int hasB = (j + 1 < c);
      int iB = hasB ? ((j + 1 < cl) ? __shfl(myIdx, j + 1) : es[j + 1]) : iA;
      int x = half ? iB : iA;
      uint2 v = *(const uint2*)&sU[(size_t)x * 64 + 2 * sl];
      if (half && !hasB) { v.x = 0u; v.y = 0u; }
      a0 += bfLo(v.x); a1 += bfHi(v.x); a2 += bfLo(v.y); a3 += bfHi(v.y);
    }
    a0 += __shfl_xor(a0, 32);
    a1 += __shfl_xor(a1, 32);
    a2 += __shfl_xor(a2, 32);
    a3 += __shfl_xor(a3, 32);
    a0 *= dv; a1 *= dv; a2 *= dv; a3 *= dv;  // t[4*sl + r]

    // ---- row-GEMM vs LDS W; t[4q+r] read from lane q ----
    if constexpr (NFO == 128) {
      float o0 = 0.f, o1 = 0.f;
      #pragma unroll
      for (int q = 0; q < 32; q++) {
        float t0 = __shfl(a0, q);
        float t1 = __shfl(a1, q);
        float t2 = __shfl(a2, q);
        float t3 = __shfl(a3, q);
        float2 w0 = *(const float2*)&Wl[(4 * q + 0) * 128 + 2 * lane];
        float2 w1 = *(const float2*)&Wl[(4 * q + 1) * 128 + 2 * lane];
        float2 w2 = *(const float2*)&Wl[(4 * q + 2) * 128 + 2 * lane];
        float2 w3 = *(const float2*)&Wl[(4 * q + 3) * 128 + 2 * lane];
        o0 = fmaf(t0, w0.x, o0); o1 = fmaf(t0, w0.y, o1);
        o0 = fmaf(t1, w1.x, o0); o1 = fmaf(t1, w1.y, o1);
        o0 = fmaf(t2, w2.x, o0); o1 = fmaf(t2, w2.y, o1);
        o0 = fmaf(t3, w3.x, o0); o1 = fmaf(t3, w3.y, o1);
      }
      float2 bb = *(const float2*)&bias[2 * lane];
      float r0 = o0 + bb.x, r1 = o1 + bb.y;
      if (RELU) { r0 = fmaxf(r0, 0.f); r1 = fmaxf(r1, 0.f); }
      *(float2*)&out[(size_t)node * 128 + 2 * lane] = make_float2(r0, r1);
    } else {
      float o0 = 0.f;
      #pragma unroll
      for (int q = 0; q < 32; q++) {
        float t0 = __shfl(a0, q);
        float t1 = __shfl(a1, q);
        float t2 = __shfl(a2, q);
        float t3 = __shfl(a3, q);
        o0 = fmaf(t0, Wl[(4 * q + 0) * NFO + lane], o0);
        o0 = fmaf(t1, Wl[(4 * q + 1) * NFO + lane], o0);
        o0 = fmaf(t2, Wl[(4 * q + 2) * NFO + lane], o0);
        o0 = fmaf(t3, Wl[(4 * q + 3) * NFO + lane], o0);
      }
      float r0 = o0 + bias[lane];
      if (RELU) r0 = fmaxf(r0, 0.f);
      out[(size_t)node * NFO + lane] = r0;
    }
  }
}

// --------------------- fp32 fused kernel (ws-fallback) ---------------------

template <int NFO, bool RELU>
__global__ __launch_bounds__(512) void k_layer_f32(const float* __restrict__ in,
                                                   const float* __restrict__ W,
                                                   const float* __restrict__ bias,
                                                   const float* __restrict__ dinv,
                                                   const int* __restrict__ eSrc,
                                                   const int* __restrict__ rowStart,
                                                   const int* __restrict__ cnt,
                                                   float* __restrict__ out, int n) {
  __shared__ float Wl[128 * NFO];
  for (int t = threadIdx.x; t < 128 * NFO; t += 512) Wl[t] = W[t];
  __syncthreads();
  const int wid = threadIdx.x >> 6, lane = threadIdx.x & 63;
  for (int node = blockIdx.x * 8 + wid; node < n; node += gridDim.x * 8) {
    const int s = rowStart[node], c = cnt[node];
    const int* es = eSrc + s;
    const float dv = dinv[node];
    float2 x2 = *(const float2*)&in[(size_t)node * 128 + 2 * lane];
    float ax = dv * x2.x, ay = dv * x2.y;
    int j = 0;
    for (; j + 4 <= c; j += 4) {
      int s0 = es[j], s1 = es[j + 1], s2 = es[j + 2], s3 = es[j + 3];
      float d0 = dinv[s0], d1 = dinv[s1], d2 = dinv[s2], d3 = dinv[s3];
      float2 v0 = *(const float2*)&in[(size_t)s0 * 128 + 2 * lane];
      float2 v1 = *(const float2*)&in[(size_t)s1 * 128 + 2 * lane];
      float2 v2 = *(const float2*)&in[(size_t)s2 * 128 + 2 * lane];
      float2 v3 = *(const float2*)&in[(size_t)s3 * 128 + 2 * lane];
      ax = fmaf(d0, v0.x, ax); ay = fmaf(d0, v0.y, ay);
      ax = fmaf(d1, v1.x, ax); ay = fmaf(d1, v1.y, ay);
      ax = fmaf(d2, v2.x, ax); ay = fmaf(d2, v2.y, ay);
      ax = fmaf(d3, v3.x, ax); ay = fmaf(d3, v3.y, ay);
    }
    for (; j < c; j++) {
      int sj = es[j];
      float dj = dinv[sj];
      float2 v = *(const float2*)&in[(size_t)sj * 128 + 2 * lane];
      ax = fmaf(dj, v.x, ax); ay = fmaf(dj, v.y, ay);
    }
    ax *= dv; ay *= dv;
    if constexpr (NFO == 128) {
      float o0 = 0.f, o1 = 0.f;
      #pragma unroll
      for (int kk = 0; kk < 64; kk++) {
        float xa = __shfl(ax, kk);
        float xb = __shfl(ay, kk);
        float2 wA = *(const float2*)&Wl[(2 * kk) * 128 + 2 * lane];
        float2 wB = *(const float2*)&Wl[(2 * kk + 1) * 128 + 2 * lane];
        o0 = fmaf(xa, wA.x, o0); o1 = fmaf(xa, wA.y, o1);
        o0 = fmaf(xb, wB.x, o0); o1 = fmaf(xb, wB.y, o1);
      }
      float2 bb = *(const float2*)&bias[2 * lane];
      float r0 = o0 + bb.x, r1 = o1 + bb.y;
      if (RELU) { r0 = fmaxf(r0, 0.f); r1 = fmaxf(r1, 0.f); }
      *(float2*)&out[(size_t)node * 128 + 2 * lane] = make_float2(r0, r1);
    } else {
      float o0 = 0.f;
      #pragma unroll
      for (int kk = 0; kk < 64; kk++) {
        float xa = __shfl(ax, kk);
        float xb = __shfl(ay, kk);
        o0 = fmaf(xa, Wl[(2 * kk) * NFO + lane], o0);
        o0 = fmaf(xb, Wl[(2 * kk + 1) * NFO + lane], o0);
      }
      float r0 = o0 + bias[lane];
      if (RELU) r0 = fmaxf(r0, 0.f);
      out[(size_t)node * NFO + lane] = r0;
    }
  }
}

// ---------------------------------------------------------------------------

extern "C" void kernel_launch(void* const* d_in, const int* in_sizes, int n_in,
                              void* d_out, int out_size, void* d_ws, size_t ws_size,
                              hipStream_t stream) {
  const float* x  = (const float*)d_in[0];
  const int*   ei = (const int*)d_in[1];
  const float* W1 = (const float*)d_in[2];
  const float* b1 = (const float*)d_in[3];
  const float* W2 = (const float*)d_in[4];
  const float* b2 = (const float*)d_in[5];
  const float* W3 = (const float*)d_in[6];
  const float* b3 = (const float*)d_in[7];

  const int N = in_sizes[0] / 128;
  const int E = in_sizes[1] / 2;
  const int* src = ei;
  const int* dst = ei + E;

  char* ws = (char*)d_ws;
  size_t off = 0;
  auto alloc = [&](size_t bytes) -> void* {
    void* p = ws + off;
    off = (off + bytes + 255) & ~(size_t)255;
    return p;
  };
  int*   cnt      = (int*)alloc((size_t)N * 4);
  int*   fillPos  = (int*)alloc((size_t)N * 4);
  int*   rowStart = (int*)alloc((size_t)N * 4);
  float* dinv     = (float*)alloc((size_t)N * 4);
  int*   bsum     = (int*)alloc(512);
  int*   eSrc     = (int*)alloc((size_t)E * 4);
  unsigned* sU    = (unsigned*)alloc((size_t)N * 64 * 4);  // bf16 rows, 256B
  const bool fast = (ws_size >= off);                       // ~33.7 MB

  float* y    = (float*)d_out;          // [N,64]
  float* out1 = y + (size_t)N * 64;     // [N,128]
  float* out2 = out1 + (size_t)N * 128; // [N,128]

  // ---- CSR build ----
  k_zero<<<(N + 255) / 256, 256, 0, stream>>>(cnt, fillPos, N);
  k_deg<<<2048, 256, 0, stream>>>(dst, cnt, E);
  k_dinv<<<(N + 255) / 256, 256, 0, stream>>>(cnt, dinv, N);
  int nChunks = (N + 1023) / 1024;
  k_scan1<<<nChunks, 256, 0, stream>>>(cnt, rowStart, bsum, N);
  k_scan2<<<1, 128, 0, stream>>>(bsum, nChunks);
  k_scan3<<<(N + 255) / 256, 256, 0, stream>>>(rowStart, bsum, N);
  k_fill<<<2048, 256, 0, stream>>>(src, dst, rowStart, fillPos, eSrc, E);

  // ---- layers ----
  if (fast) {
    const int nQuads = N * 16;
    const int sBlocks = (nQuads + 255) / 256;
    k_scale<<<sBlocks, 256, 0, stream>>>(x, dinv, (uint4*)sU, nQuads);
    k_layer_bf4<128, true ><<<1024, 512, 0, stream>>>(sU, W1, b1, dinv, eSrc, rowStart, cnt, out1, N);
    k_scale<<<sBlocks, 256, 0, stream>>>(out1, dinv, (uint4*)sU, nQuads);
    k_layer_bf4<128, true ><<<1024, 512, 0, stream>>>(sU, W2, b2, dinv, eSrc, rowStart, cnt, out2, N);
    k_scale<<<sBlocks, 256, 0, stream>>>(out2, dinv, (uint4*)sU, nQuads);
    k_layer_bf4<64,  false><<<1024, 512, 0, stream>>>(sU, W3, b3, dinv, eSrc, rowStart, cnt, y,    N);
  } else {
    k_layer_f32<128, true ><<<1024, 512, 0, stream>>>(x,    W1, b1, dinv, eSrc, rowStart, cnt, out1, N);
    k_layer_f32<128, true ><<<1024, 512, 0, stream>>>(out1, W2, b2, dinv, eSrc, rowStart, cnt, out2, N);
    k_layer_f32<64,  false><<<1024, 512, 0, stream>>>(out2, W3, b3, dinv, eSrc, rowStart, cnt, y,    N);
  }
}